// Round 7
// baseline (1300.114 us; speedup 1.0000x reference)
//
#include <hip/hip_runtime.h>
#include <stdint.h>

// ---------- types ----------
typedef __bf16  bf16x8 __attribute__((ext_vector_type(8)));
typedef short   s16x8  __attribute__((ext_vector_type(8)));
typedef float   f32x4  __attribute__((ext_vector_type(4)));

__device__ inline short f2bf(float f) {
  union { float f; uint32_t u; } v; v.f = f;
  uint32_t r = v.u + 0x7FFFu + ((v.u >> 16) & 1u);   // RNE
  return (short)(r >> 16);
}
__device__ inline uint32_t f2bf_u(float f) { return (uint32_t)(uint16_t)f2bf(f); }

// B=4, H=W=D=16 -> N=4096 tokens/batch, C=512, GROUPS=32 (16 ch/group)

// ---------- GroupNorm stats ----------
__global__ __launch_bounds__(256) void gn_stats_k(const float* __restrict__ x,
                                                  float* __restrict__ mean,
                                                  float* __restrict__ rstd) {
  int bg = blockIdx.x;
  int b = bg >> 5, g = bg & 31;
  int tid = threadIdx.x;
  const float* base = x + (size_t)b * 4096 * 512 + g * 16;
  float s = 0.f, q = 0.f;
  for (int i = tid; i < 16384; i += 256) {
    int n = i >> 2, sub = i & 3;
    float4 v = *(const float4*)(base + (size_t)n * 512 + sub * 4);
    s += v.x + v.y + v.z + v.w;
    q += v.x * v.x + v.y * v.y + v.z * v.z + v.w * v.w;
  }
  for (int off = 32; off > 0; off >>= 1) {
    s += __shfl_down(s, off, 64);
    q += __shfl_down(q, off, 64);
  }
  __shared__ float rs[4], rq[4];
  int w = tid >> 6;
  if ((tid & 63) == 0) { rs[w] = s; rq[w] = q; }
  __syncthreads();
  if (tid == 0) {
    float S = rs[0] + rs[1] + rs[2] + rs[3];
    float Q = rq[0] + rq[1] + rq[2] + rq[3];
    float m = S * (1.f / 65536.f);
    float var = Q * (1.f / 65536.f) - m * m;
    mean[bg] = m;
    rstd[bg] = rsqrtf(var + 1e-6f);
  }
}

// ---------- GN apply -> bf16 h ----------
__global__ __launch_bounds__(256) void gn_apply_k(const float* __restrict__ x,
                                                  const float* __restrict__ mean,
                                                  const float* __restrict__ rstd,
                                                  const float* __restrict__ sc,
                                                  const float* __restrict__ bi,
                                                  short* __restrict__ h) {
  size_t i4 = ((size_t)blockIdx.x * 256 + threadIdx.x) * 4;
  int c = (int)(i4 & 511);
  int tok = (int)(i4 >> 9);
  int b = tok >> 12;
  int bg = b * 32 + (c >> 4);
  float m = mean[bg], r = rstd[bg];
  float4 v = *(const float4*)(x + i4);
  float4 s = *(const float4*)(sc + c);
  float4 bb = *(const float4*)(bi + c);
  short4 o;
  o.x = f2bf((v.x - m) * r * s.x + bb.x);
  o.y = f2bf((v.y - m) * r * s.y + bb.y);
  o.z = f2bf((v.z - m) * r * s.z + bb.z);
  o.w = f2bf((v.w - m) * r * s.w + bb.w);
  *(short4*)(h + i4) = o;
}

// ---------- weights -> bf16, transposed ----------
__global__ __launch_bounds__(256) void wconv_k(const float* __restrict__ wq,
                                               const float* __restrict__ wk,
                                               const float* __restrict__ wv,
                                               const float* __restrict__ wp,
                                               short* __restrict__ wt) {
  int i = blockIdx.x * 256 + threadIdx.x;
  int widx = i >> 18, rem = i & 262143;
  int c = rem >> 9, j = rem & 511;
  const float* w = widx == 0 ? wq : widx == 1 ? wk : widx == 2 ? wv : wp;
  wt[(size_t)widx * 262144 + (size_t)j * 512 + c] = f2bf(w[(size_t)c * 512 + j]);
}

// ---------- GEMM (unchanged, validated) ----------
__global__ __launch_bounds__(256) void gemm_k(const short* __restrict__ A,
                                              const short* __restrict__ Bt,
                                              const float* __restrict__ bias,
                                              const float* __restrict__ xres,
                                              short* __restrict__ outb,
                                              float* __restrict__ outf, int mode) {
  __shared__ __attribute__((aligned(16))) short As[128 * 32];
  __shared__ __attribute__((aligned(16))) short Bs[128 * 32];
  int tid = threadIdx.x;
  int w = tid >> 6, lane = tid & 63, quad = lane >> 4, mrow = lane & 15;
  int wm = w >> 1, wn = w & 1;
  int m0 = blockIdx.x * 128, n0 = blockIdx.y * 128;

  const f32x4 fz = {0.f, 0.f, 0.f, 0.f};
  f32x4 acc[4][4];
#pragma unroll
  for (int i = 0; i < 4; i++)
#pragma unroll
    for (int j = 0; j < 4; j++) acc[i][j] = fz;

  int srow = tid >> 2;
  int scol = (tid & 3) * 8;

  for (int k0 = 0; k0 < 512; k0 += 32) {
    __syncthreads();
#pragma unroll
    for (int i = 0; i < 2; i++) {
      const short* ga = A + (size_t)(m0 + i * 64 + srow) * 512 + k0 + scol;
      const short* gb = Bt + (size_t)(n0 + i * 64 + srow) * 512 + k0 + scol;
      char* la = (char*)As + i * 4096 + w * 1024;
      char* lb = (char*)Bs + i * 4096 + w * 1024;
      __builtin_amdgcn_global_load_lds((__attribute__((address_space(1))) void*)ga,
                                       (__attribute__((address_space(3))) void*)la, 16, 0, 0);
      __builtin_amdgcn_global_load_lds((__attribute__((address_space(1))) void*)gb,
                                       (__attribute__((address_space(3))) void*)lb, 16, 0, 0);
    }
    __syncthreads();
    bf16x8 af[4], bfv[4];
#pragma unroll
    for (int mi = 0; mi < 4; mi++)
      af[mi] = *(const bf16x8*)&As[(wm * 64 + mi * 16 + mrow) * 32 + quad * 8];
#pragma unroll
    for (int ni = 0; ni < 4; ni++)
      bfv[ni] = *(const bf16x8*)&Bs[(wn * 64 + ni * 16 + mrow) * 32 + quad * 8];
#pragma unroll
    for (int mi = 0; mi < 4; mi++)
#pragma unroll
      for (int ni = 0; ni < 4; ni++)
        acc[mi][ni] = __builtin_amdgcn_mfma_f32_16x16x32_bf16(af[mi], bfv[ni], acc[mi][ni], 0, 0, 0);
  }

#pragma unroll
  for (int mi = 0; mi < 4; mi++)
#pragma unroll
    for (int ni = 0; ni < 4; ni++) {
      int col = n0 + wn * 64 + ni * 16 + mrow;
      float bv = bias[col];
#pragma unroll
      for (int r = 0; r < 4; r++) {
        int row = m0 + wm * 64 + mi * 16 + quad * 4 + r;
        float val = acc[mi][ni][r] + bv;
        if (mode == 0) {
          outb[(size_t)row * 512 + col] = f2bf(val);
        } else if (mode == 1) {
          int b = row >> 12, t = row & 4095;
          outb[(size_t)b * (512 * 4096) + (size_t)col * 4096 + t] = f2bf(val);
        } else {
          size_t idx = (size_t)row * 512 + col;
          outf[idx] = xres[idx] + val;
        }
      }
    }
}

// ---------- flash attention v5: O-channel-split, replicated softmax ----------
// 1024 blocks x 4 waves; block = 16 queries, all 4096 keys (128 iters of 32).
// Wave w owns O-channels [w*128, w*128+128): oacc is only 8 f32x4 = 32 VGPRs.
// All 4 waves compute identical S + online softmax (QK replicated x4 -- MFMA
// has ~50x headroom) -> ZERO cross-wave communication; the only barrier is
// K-tile LDS double-buffer staging (v3's validated layout).
// V: per-wave 128-ch slice, software-pipelined register prefetch (vn at iter
// top, consumed next iter). P-transpose: bf16-pair pack -> 8 shuffles.
// Register budget ~210 (qf 64 + oacc 32 + vc/vn 64 + temps) -> true 2 waves/SIMD.
__global__ __launch_bounds__(256, 2) void flash_k(const short* __restrict__ Q,
                                                  const short* __restrict__ K,
                                                  const short* __restrict__ Vt,
                                                  short* __restrict__ O) {
  __shared__ __attribute__((aligned(16))) short Ks[2][16384];   // 64 KB
  int L = blockIdx.x;
  int b = (L & 7) >> 1;                       // batch -> XCD pair (L%8 round-robin)
  int qt = ((L >> 3) << 1) | (L & 1);         // 0..255 q-tile within batch
  int q0 = qt * 16;
  int tid = threadIdx.x;
  int w = tid >> 6, lane = tid & 63, quad = lane >> 4, m = lane & 15;
  const size_t batch_off = (size_t)b * 4096 * 512;
  const float scale2 = 0.06375872f;           // 512^-0.5 * log2(e)

  // Q fragments (B-operand: n=query=lane&15, k=ch=quad*8+j), 16 steps = 512 ch
  const short* Qrow = Q + batch_off + (size_t)(q0 + m) * 512;
  bf16x8 qf[16];
#pragma unroll
  for (int s = 0; s < 16; s++)
    qf[s] = *(const bf16x8*)&Qrow[s * 32 + quad * 8];

  const f32x4 fz = {0.f, 0.f, 0.f, 0.f};
  f32x4 oacc[8];
#pragma unroll
  for (int i = 0; i < 8; i++) oacc[i] = fz;
  float mrun = -1e30f, lrun = 0.f;

  // ---- stage K-tile for iter 0 into buf 0 (wave w stages ch-quarter w) ----
#pragma unroll
  for (int i = 0; i < 8; i++) {
    int ksb = w * 16 + i * 2;
    const short* gk = K + batch_off + (size_t)(lane & 31) * 512 + (size_t)(ksb + (lane >> 5)) * 8;
    __builtin_amdgcn_global_load_lds((__attribute__((address_space(1))) void*)gk,
                                     (__attribute__((address_space(3))) void*)&Ks[0][ksb * 256],
                                     16, 0, 0);
  }

  // ---- preload V slice for iter 0 (wave's 128 channels, B-frag layout) ----
  const short* Vbase = Vt + batch_off + (size_t)(w * 128 + m) * 4096 + quad * 8;
  bf16x8 vc[8];
#pragma unroll
  for (int ct = 0; ct < 8; ct++)
    vc[ct] = *(const bf16x8*)&Vbase[(size_t)ct * 16 * 4096];

#pragma unroll 1
  for (int it = 0; it < 128; ++it) {
    int t0 = it * 32;
    int buf = it & 1;
    __syncthreads();   // buf staged (vmcnt drain) + all waves done reading buf^1
    if (it < 127) {
      int t1 = t0 + 32;
#pragma unroll
      for (int i = 0; i < 8; i++) {
        int ksb = w * 16 + i * 2;
        const short* gk = K + batch_off + (size_t)(t1 + (lane & 31)) * 512 +
                          (size_t)(ksb + (lane >> 5)) * 8;
        __builtin_amdgcn_global_load_lds((__attribute__((address_space(1))) void*)gk,
                                         (__attribute__((address_space(3))) void*)&Ks[buf ^ 1][ksb * 256],
                                         16, 0, 0);
      }
    }
    // ---- V prefetch for NEXT iter (full-iteration latency slack) ----
    bf16x8 vn[8];
    if (it < 127) {
      int t1 = t0 + 32;
#pragma unroll
      for (int ct = 0; ct < 8; ct++)
        vn[ct] = *(const bf16x8*)&Vbase[(size_t)ct * 16 * 4096 + t1];
    }
    // ---- QK^T (transposed): row=key, col=query; 4 acc chains ----
    f32x4 s0a = fz, s0b = fz, s1a = fz, s1b = fz;
#pragma unroll
    for (int s = 0; s < 16; s++) {
      bf16x8 k0 = *(const bf16x8*)&Ks[buf][((s * 4 + quad) * 32 + m) * 8];
      bf16x8 k1 = *(const bf16x8*)&Ks[buf][((s * 4 + quad) * 32 + 16 + m) * 8];
      if (s & 1) {
        s0b = __builtin_amdgcn_mfma_f32_16x16x32_bf16(k0, qf[s], s0b, 0, 0, 0);
        s1b = __builtin_amdgcn_mfma_f32_16x16x32_bf16(k1, qf[s], s1b, 0, 0, 0);
      } else {
        s0a = __builtin_amdgcn_mfma_f32_16x16x32_bf16(k0, qf[s], s0a, 0, 0, 0);
        s1a = __builtin_amdgcn_mfma_f32_16x16x32_bf16(k1, qf[s], s1a, 0, 0, 0);
      }
    }
    // ---- per-lane online softmax for query m (identical in all 4 waves) ----
    float v0[4], v1[4];
    float mx = -1e30f;
#pragma unroll
    for (int r = 0; r < 4; r++) {
      v0[r] = (s0a[r] + s0b[r]) * scale2;
      v1[r] = (s1a[r] + s1b[r]) * scale2;
      mx = fmaxf(mx, fmaxf(v0[r], v1[r]));
    }
    mx = fmaxf(mx, __shfl_xor(mx, 16, 64));
    mx = fmaxf(mx, __shfl_xor(mx, 32, 64));
    float mn = fmaxf(mrun, mx);
    float alpha = exp2f(mrun - mn);
    mrun = mn;
    float p0[4], p1[4];
    float sum = 0.f;
#pragma unroll
    for (int r = 0; r < 4; r++) {
      p0[r] = exp2f(v0[r] - mn);
      p1[r] = exp2f(v1[r] - mn);
      sum += p0[r] + p1[r];
    }
    sum += __shfl_xor(sum, 16, 64);
    sum += __shfl_xor(sum, 32, 64);
    lrun = lrun * alpha + sum;
    // ---- rescale O (only 32 mults now) ----
    if (__any(alpha != 1.0f)) {
      float al[4];
#pragma unroll
      for (int r = 0; r < 4; r++) al[r] = __shfl(alpha, quad * 4 + r, 64);
#pragma unroll
      for (int i = 0; i < 8; i++)
#pragma unroll
        for (int r = 0; r < 4; r++) oacc[i][r] *= al[r];
    }
    // ---- P -> A-frag: pack (p0,p1) as bf16 pair, then 8 shuffles ----
    uint32_t pk[4];
#pragma unroll
    for (int r = 0; r < 4; r++)
      pk[r] = f2bf_u(p0[r]) | (f2bf_u(p1[r]) << 16);
    s16x8 pfs;
#pragma unroll
    for (int j = 0; j < 8; j++) {
      int src = ((((quad & 1) * 2 + (j >> 2)) << 4) | m);
      uint32_t pv = (uint32_t)__shfl((int)pk[j & 3], src, 64);
      pfs[j] = (short)(quad < 2 ? (pv & 0xffffu) : (pv >> 16));
    }
    bf16x8 pf = __builtin_bit_cast(bf16x8, pfs);
    // ---- O += P @ V on this wave's 128-ch slice (vc prefetched last iter) ----
#pragma unroll
    for (int ct = 0; ct < 8; ct++)
      oacc[ct] = __builtin_amdgcn_mfma_f32_16x16x32_bf16(pf, vc[ct], oacc[ct], 0, 0, 0);
    if (it < 127) {
#pragma unroll
      for (int ct = 0; ct < 8; ct++) vc[ct] = vn[ct];
    }
  }
  // ---- epilogue: O /= l, store this wave's 128-ch slice ----
  float invl = 1.f / lrun;
  float ir[4];
#pragma unroll
  for (int r = 0; r < 4; r++) ir[r] = __shfl(invl, quad * 4 + r, 64);
#pragma unroll
  for (int ct = 0; ct < 8; ct++)
#pragma unroll
    for (int r = 0; r < 4; r++) {
      int row = q0 + quad * 4 + r;
      int col = w * 128 + ct * 16 + m;
      O[batch_off + (size_t)row * 512 + col] = f2bf(oacc[ct][r] * ir[r]);
    }
}

extern "C" void kernel_launch(void* const* d_in, const int* in_sizes, int n_in,
                              void* d_out, int out_size, void* d_ws, size_t ws_size,
                              hipStream_t stream) {
  const float* x  = (const float*)d_in[0];
  const float* gs = (const float*)d_in[1];
  const float* gb = (const float*)d_in[2];
  const float* wq = (const float*)d_in[3];
  const float* bq = (const float*)d_in[4];
  const float* wk = (const float*)d_in[5];
  const float* bk = (const float*)d_in[6];
  const float* wv = (const float*)d_in[7];
  const float* bv = (const float*)d_in[8];
  const float* wp = (const float*)d_in[9];
  const float* bp = (const float*)d_in[10];
  float* out = (float*)d_out;

  // ---- workspace layout (~34 MB; Q/K live in d_out until final GEMM) ----
  char* ws = (char*)d_ws;
  float* mean = (float*)ws;                               // 128 f
  float* rstd = (float*)(ws + 512);                       // 128 f
  short* h    = (short*)(ws + 1024);                      // 16384*512 bf16 (16.78 MB)
  short* wt   = (short*)(ws + 1024 + 16777216);           // 4*512*512 bf16 (2 MB)
  short* Vt   = (short*)(ws + 1024 + 16777216 + 2097152); // [b][c][t] bf16 (16.78 MB)
  short* Qb   = (short*)d_out;                            // 16.78 MB in d_out
  short* Kb   = Qb + 8388608;                             // 16.78 MB in d_out
  short* Ob   = h;                                        // alias: h dead after V GEMM

  gn_stats_k<<<128, 256, 0, stream>>>(x, mean, rstd);
  gn_apply_k<<<8192, 256, 0, stream>>>(x, mean, rstd, gs, gb, h);
  wconv_k<<<4096, 256, 0, stream>>>(wq, wk, wv, wp, wt);
  dim3 gg(128, 4);
  gemm_k<<<gg, 256, 0, stream>>>(h, wt,          bq, nullptr, Qb, nullptr, 0);
  gemm_k<<<gg, 256, 0, stream>>>(h, wt + 262144, bk, nullptr, Kb, nullptr, 0);
  gemm_k<<<gg, 256, 0, stream>>>(h, wt + 524288, bv, nullptr, Vt, nullptr, 1);
  flash_k<<<1024, 256, 0, stream>>>(Qb, Kb, Vt, Ob);
  // final projection reads Ob (=h space), x, wt_p; writes d_out (overwrites Q/K)
  gemm_k<<<gg, 256, 0, stream>>>(Ob, wt + 786432, bp, x, nullptr, out, 2);
}

// Round 8
// 768.556 us; speedup vs baseline: 1.6916x; 1.6916x over previous
//
#include <hip/hip_runtime.h>
#include <stdint.h>

// ---------- types ----------
typedef __bf16  bf16x8 __attribute__((ext_vector_type(8)));
typedef short   s16x8  __attribute__((ext_vector_type(8)));
typedef float   f32x4  __attribute__((ext_vector_type(4)));

__device__ inline short f2bf(float f) {
  union { float f; uint32_t u; } v; v.f = f;
  uint32_t r = v.u + 0x7FFFu + ((v.u >> 16) & 1u);   // RNE
  return (short)(r >> 16);
}
__device__ inline uint32_t f2bf_u(float f) { return (uint32_t)(uint16_t)f2bf(f); }

// B=4, H=W=D=16 -> N=4096 tokens/batch, C=512, GROUPS=32 (16 ch/group)

// ---------- GroupNorm stats ----------
__global__ __launch_bounds__(256) void gn_stats_k(const float* __restrict__ x,
                                                  float* __restrict__ mean,
                                                  float* __restrict__ rstd) {
  int bg = blockIdx.x;
  int b = bg >> 5, g = bg & 31;
  int tid = threadIdx.x;
  const float* base = x + (size_t)b * 4096 * 512 + g * 16;
  float s = 0.f, q = 0.f;
  for (int i = tid; i < 16384; i += 256) {
    int n = i >> 2, sub = i & 3;
    float4 v = *(const float4*)(base + (size_t)n * 512 + sub * 4);
    s += v.x + v.y + v.z + v.w;
    q += v.x * v.x + v.y * v.y + v.z * v.z + v.w * v.w;
  }
  for (int off = 32; off > 0; off >>= 1) {
    s += __shfl_down(s, off, 64);
    q += __shfl_down(q, off, 64);
  }
  __shared__ float rs[4], rq[4];
  int w = tid >> 6;
  if ((tid & 63) == 0) { rs[w] = s; rq[w] = q; }
  __syncthreads();
  if (tid == 0) {
    float S = rs[0] + rs[1] + rs[2] + rs[3];
    float Q = rq[0] + rq[1] + rq[2] + rq[3];
    float m = S * (1.f / 65536.f);
    float var = Q * (1.f / 65536.f) - m * m;
    mean[bg] = m;
    rstd[bg] = rsqrtf(var + 1e-6f);
  }
}

// ---------- GN apply -> bf16 h ----------
__global__ __launch_bounds__(256) void gn_apply_k(const float* __restrict__ x,
                                                  const float* __restrict__ mean,
                                                  const float* __restrict__ rstd,
                                                  const float* __restrict__ sc,
                                                  const float* __restrict__ bi,
                                                  short* __restrict__ h) {
  size_t i4 = ((size_t)blockIdx.x * 256 + threadIdx.x) * 4;
  int c = (int)(i4 & 511);
  int tok = (int)(i4 >> 9);
  int b = tok >> 12;
  int bg = b * 32 + (c >> 4);
  float m = mean[bg], r = rstd[bg];
  float4 v = *(const float4*)(x + i4);
  float4 s = *(const float4*)(sc + c);
  float4 bb = *(const float4*)(bi + c);
  short4 o;
  o.x = f2bf((v.x - m) * r * s.x + bb.x);
  o.y = f2bf((v.y - m) * r * s.y + bb.y);
  o.z = f2bf((v.z - m) * r * s.z + bb.z);
  o.w = f2bf((v.w - m) * r * s.w + bb.w);
  *(short4*)(h + i4) = o;
}

// ---------- weights -> bf16, transposed ----------
__global__ __launch_bounds__(256) void wconv_k(const float* __restrict__ wq,
                                               const float* __restrict__ wk,
                                               const float* __restrict__ wv,
                                               const float* __restrict__ wp,
                                               short* __restrict__ wt) {
  int i = blockIdx.x * 256 + threadIdx.x;
  int widx = i >> 18, rem = i & 262143;
  int c = rem >> 9, j = rem & 511;
  const float* w = widx == 0 ? wq : widx == 1 ? wk : widx == 2 ? wv : wp;
  wt[(size_t)widx * 262144 + (size_t)j * 512 + c] = f2bf(w[(size_t)c * 512 + j]);
}

// ---------- GEMM (unchanged, validated) ----------
__global__ __launch_bounds__(256) void gemm_k(const short* __restrict__ A,
                                              const short* __restrict__ Bt,
                                              const float* __restrict__ bias,
                                              const float* __restrict__ xres,
                                              short* __restrict__ outb,
                                              float* __restrict__ outf, int mode) {
  __shared__ __attribute__((aligned(16))) short As[128 * 32];
  __shared__ __attribute__((aligned(16))) short Bs[128 * 32];
  int tid = threadIdx.x;
  int w = tid >> 6, lane = tid & 63, quad = lane >> 4, mrow = lane & 15;
  int wm = w >> 1, wn = w & 1;
  int m0 = blockIdx.x * 128, n0 = blockIdx.y * 128;

  const f32x4 fz = {0.f, 0.f, 0.f, 0.f};
  f32x4 acc[4][4];
#pragma unroll
  for (int i = 0; i < 4; i++)
#pragma unroll
    for (int j = 0; j < 4; j++) acc[i][j] = fz;

  int srow = tid >> 2;
  int scol = (tid & 3) * 8;

  for (int k0 = 0; k0 < 512; k0 += 32) {
    __syncthreads();
#pragma unroll
    for (int i = 0; i < 2; i++) {
      const short* ga = A + (size_t)(m0 + i * 64 + srow) * 512 + k0 + scol;
      const short* gb = Bt + (size_t)(n0 + i * 64 + srow) * 512 + k0 + scol;
      char* la = (char*)As + i * 4096 + w * 1024;
      char* lb = (char*)Bs + i * 4096 + w * 1024;
      __builtin_amdgcn_global_load_lds((__attribute__((address_space(1))) void*)ga,
                                       (__attribute__((address_space(3))) void*)la, 16, 0, 0);
      __builtin_amdgcn_global_load_lds((__attribute__((address_space(1))) void*)gb,
                                       (__attribute__((address_space(3))) void*)lb, 16, 0, 0);
    }
    __syncthreads();
    bf16x8 af[4], bfv[4];
#pragma unroll
    for (int mi = 0; mi < 4; mi++)
      af[mi] = *(const bf16x8*)&As[(wm * 64 + mi * 16 + mrow) * 32 + quad * 8];
#pragma unroll
    for (int ni = 0; ni < 4; ni++)
      bfv[ni] = *(const bf16x8*)&Bs[(wn * 64 + ni * 16 + mrow) * 32 + quad * 8];
#pragma unroll
    for (int mi = 0; mi < 4; mi++)
#pragma unroll
      for (int ni = 0; ni < 4; ni++)
        acc[mi][ni] = __builtin_amdgcn_mfma_f32_16x16x32_bf16(af[mi], bfv[ni], acc[mi][ni], 0, 0, 0);
  }

#pragma unroll
  for (int mi = 0; mi < 4; mi++)
#pragma unroll
    for (int ni = 0; ni < 4; ni++) {
      int col = n0 + wn * 64 + ni * 16 + mrow;
      float bv = bias[col];
#pragma unroll
      for (int r = 0; r < 4; r++) {
        int row = m0 + wm * 64 + mi * 16 + quad * 4 + r;
        float val = acc[mi][ni][r] + bv;
        if (mode == 0) {
          outb[(size_t)row * 512 + col] = f2bf(val);
        } else if (mode == 1) {
          int b = row >> 12, t = row & 4095;
          outb[(size_t)b * (512 * 4096) + (size_t)col * 4096 + t] = f2bf(val);
        } else {
          size_t idx = (size_t)row * 512 + col;
          outf[idx] = xres[idx] + val;
        }
      }
    }
}

// ---------- flash attention v6: v3 + V through LDS (all global traffic async) ----------
// 256 blocks x 4 waves; wave = 16 queries x all 512 channels (v3 partitioning,
// FETCH ~41 MB). BOTH K and V tiles (32 KB each) double-buffered in LDS via
// global_load_lds (zero VGPR cost -> compiler cannot re-sink the prefetch),
// staged one iteration ahead, drained by the single per-iter barrier.
// V is staged FRAG-MAJOR: 16B unit index = ct*64 + lane, so the PV frag read
// is the canonical conflict-free "base + lane*16" pattern, and the staging
// dst is exactly the wave-uniform-base+lane*16 the HW provides.
// In-iter chain is now pure LDS->MFMA->VALU: QK -> softmax -> PV. ~230 VGPR,
// 1 wave/SIMD by design (the bet is latency elimination, not hiding).
__global__ __launch_bounds__(256) void flash_k(const short* __restrict__ Q,
                                               const short* __restrict__ K,
                                               const short* __restrict__ Vt,
                                               short* __restrict__ O) {
  __shared__ __attribute__((aligned(16))) short Ks[2][16384];   // 64 KB
  __shared__ __attribute__((aligned(16))) short Vs[2][16384];   // 64 KB
  int L = blockIdx.x;
  int b = (L & 7) >> 1;                       // batch -> XCD pair (L%8 round-robin)
  int q0 = (((L >> 3) << 1) | (L & 1)) * 64;
  int tid = threadIdx.x;
  int w = tid >> 6, lane = tid & 63, quad = lane >> 4, m = lane & 15;
  const size_t batch_off = (size_t)b * 4096 * 512;
  const float scale2 = 0.06375872f;           // 512^-0.5 * log2(e)

  // Q fragments (B-operand: n=query=lane&15, k=ch=quad*8+j), 16 steps = 512 ch
  const short* Qrow = Q + batch_off + (size_t)(q0 + w * 16 + m) * 512;
  bf16x8 qf[16];
#pragma unroll
  for (int s = 0; s < 16; s++)
    qf[s] = *(const bf16x8*)&Qrow[s * 32 + quad * 8];

  const f32x4 fz = {0.f, 0.f, 0.f, 0.f};
  f32x4 oacc[32];
#pragma unroll
  for (int i = 0; i < 32; i++) oacc[i] = fz;
  float mrun = -1e30f, lrun = 0.f;

  // ---- prologue: stage K(0), V(0) into buf 0 ----
#pragma unroll
  for (int i = 0; i < 8; i++) {
    int ksb = w * 16 + i * 2;
    const short* gk = K + batch_off + (size_t)(lane & 31) * 512 + (size_t)(ksb + (lane >> 5)) * 8;
    __builtin_amdgcn_global_load_lds((__attribute__((address_space(1))) void*)gk,
                                     (__attribute__((address_space(3))) void*)&Ks[0][ksb * 256],
                                     16, 0, 0);
  }
#pragma unroll
  for (int i = 0; i < 8; i++) {
    int ct = w * 8 + i;
    const short* gv = Vt + batch_off + (size_t)(ct * 16 + m) * 4096 + quad * 8;
    __builtin_amdgcn_global_load_lds((__attribute__((address_space(1))) void*)gv,
                                     (__attribute__((address_space(3))) void*)&Vs[0][ct * 512],
                                     16, 0, 0);
  }

#pragma unroll 1
  for (int it = 0; it < 128; ++it) {
    int t0 = it * 32;
    int buf = it & 1;
    __syncthreads();   // staging of buf drained (vmcnt); all waves done with buf^1
    if (it < 127) {
      int t1 = t0 + 32;
#pragma unroll
      for (int i = 0; i < 8; i++) {
        int ksb = w * 16 + i * 2;
        const short* gk = K + batch_off + (size_t)(t1 + (lane & 31)) * 512 +
                          (size_t)(ksb + (lane >> 5)) * 8;
        __builtin_amdgcn_global_load_lds((__attribute__((address_space(1))) void*)gk,
                                         (__attribute__((address_space(3))) void*)&Ks[buf ^ 1][ksb * 256],
                                         16, 0, 0);
      }
#pragma unroll
      for (int i = 0; i < 8; i++) {
        int ct = w * 8 + i;
        const short* gv = Vt + batch_off + (size_t)(ct * 16 + m) * 4096 + t1 + quad * 8;
        __builtin_amdgcn_global_load_lds((__attribute__((address_space(1))) void*)gv,
                                         (__attribute__((address_space(3))) void*)&Vs[buf ^ 1][ct * 512],
                                         16, 0, 0);
      }
    }
    // ---- QK^T (transposed): row=key, col=query; 4 acc chains ----
    f32x4 s0a = fz, s0b = fz, s1a = fz, s1b = fz;
#pragma unroll
    for (int s = 0; s < 16; s++) {
      bf16x8 k0 = *(const bf16x8*)&Ks[buf][((s * 4 + quad) * 32 + m) * 8];
      bf16x8 k1 = *(const bf16x8*)&Ks[buf][((s * 4 + quad) * 32 + 16 + m) * 8];
      if (s & 1) {
        s0b = __builtin_amdgcn_mfma_f32_16x16x32_bf16(k0, qf[s], s0b, 0, 0, 0);
        s1b = __builtin_amdgcn_mfma_f32_16x16x32_bf16(k1, qf[s], s1b, 0, 0, 0);
      } else {
        s0a = __builtin_amdgcn_mfma_f32_16x16x32_bf16(k0, qf[s], s0a, 0, 0, 0);
        s1a = __builtin_amdgcn_mfma_f32_16x16x32_bf16(k1, qf[s], s1a, 0, 0, 0);
      }
    }
    // ---- per-lane online softmax for query m ----
    float v0[4], v1[4];
    float mx = -1e30f;
#pragma unroll
    for (int r = 0; r < 4; r++) {
      v0[r] = (s0a[r] + s0b[r]) * scale2;
      v1[r] = (s1a[r] + s1b[r]) * scale2;
      mx = fmaxf(mx, fmaxf(v0[r], v1[r]));
    }
    mx = fmaxf(mx, __shfl_xor(mx, 16, 64));
    mx = fmaxf(mx, __shfl_xor(mx, 32, 64));
    float mn = fmaxf(mrun, mx);
    float alpha = exp2f(mrun - mn);
    mrun = mn;
    float p0[4], p1[4];
    float sum = 0.f;
#pragma unroll
    for (int r = 0; r < 4; r++) {
      p0[r] = exp2f(v0[r] - mn);
      p1[r] = exp2f(v1[r] - mn);
      sum += p0[r] + p1[r];
    }
    sum += __shfl_xor(sum, 16, 64);
    sum += __shfl_xor(sum, 32, 64);
    lrun = lrun * alpha + sum;
    // ---- rescale O (skip when no row max changed) ----
    if (__any(alpha != 1.0f)) {
      float al[4];
#pragma unroll
      for (int r = 0; r < 4; r++) al[r] = __shfl(alpha, quad * 4 + r, 64);
#pragma unroll
      for (int i = 0; i < 32; i++)
#pragma unroll
        for (int r = 0; r < 4; r++) oacc[i][r] *= al[r];
    }
    // ---- P -> A-frag: bf16-pair pack, 8 shuffles ----
    uint32_t pk[4];
#pragma unroll
    for (int r = 0; r < 4; r++)
      pk[r] = f2bf_u(p0[r]) | (f2bf_u(p1[r]) << 16);
    s16x8 pfs;
#pragma unroll
    for (int j = 0; j < 8; j++) {
      int src = ((((quad & 1) * 2 + (j >> 2)) << 4) | m);
      uint32_t pv = (uint32_t)__shfl((int)pk[j & 3], src, 64);
      pfs[j] = (short)(quad < 2 ? (pv & 0xffffu) : (pv >> 16));
    }
    bf16x8 pf = __builtin_bit_cast(bf16x8, pfs);
    // ---- O += P @ V, V frags from LDS (conflict-free: base + lane*16) ----
#pragma unroll
    for (int ct = 0; ct < 32; ct++) {
      bf16x8 vf = *(const bf16x8*)&Vs[buf][(ct * 64 + lane) * 8];
      oacc[ct] = __builtin_amdgcn_mfma_f32_16x16x32_bf16(pf, vf, oacc[ct], 0, 0, 0);
    }
  }
  // ---- epilogue: O /= l, store bf16 row-major ----
  float invl = 1.f / lrun;
  float ir[4];
#pragma unroll
  for (int r = 0; r < 4; r++) ir[r] = __shfl(invl, quad * 4 + r, 64);
#pragma unroll
  for (int ct = 0; ct < 32; ct++)
#pragma unroll
    for (int r = 0; r < 4; r++) {
      int row = q0 + w * 16 + quad * 4 + r;
      int col = ct * 16 + m;
      O[batch_off + (size_t)row * 512 + col] = f2bf(oacc[ct][r] * ir[r]);
    }
}

extern "C" void kernel_launch(void* const* d_in, const int* in_sizes, int n_in,
                              void* d_out, int out_size, void* d_ws, size_t ws_size,
                              hipStream_t stream) {
  const float* x  = (const float*)d_in[0];
  const float* gs = (const float*)d_in[1];
  const float* gb = (const float*)d_in[2];
  const float* wq = (const float*)d_in[3];
  const float* bq = (const float*)d_in[4];
  const float* wk = (const float*)d_in[5];
  const float* bk = (const float*)d_in[6];
  const float* wv = (const float*)d_in[7];
  const float* bv = (const float*)d_in[8];
  const float* wp = (const float*)d_in[9];
  const float* bp = (const float*)d_in[10];
  float* out = (float*)d_out;

  // ---- workspace layout (~34 MB; Q/K live in d_out until final GEMM) ----
  char* ws = (char*)d_ws;
  float* mean = (float*)ws;                               // 128 f
  float* rstd = (float*)(ws + 512);                       // 128 f
  short* h    = (short*)(ws + 1024);                      // 16384*512 bf16 (16.78 MB)
  short* wt   = (short*)(ws + 1024 + 16777216);           // 4*512*512 bf16 (2 MB)
  short* Vt   = (short*)(ws + 1024 + 16777216 + 2097152); // [b][c][t] bf16 (16.78 MB)
  short* Qb   = (short*)d_out;                            // 16.78 MB in d_out
  short* Kb   = Qb + 8388608;                             // 16.78 MB in d_out
  short* Ob   = h;                                        // alias: h dead after V GEMM

  gn_stats_k<<<128, 256, 0, stream>>>(x, mean, rstd);
  gn_apply_k<<<8192, 256, 0, stream>>>(x, mean, rstd, gs, gb, h);
  wconv_k<<<4096, 256, 0, stream>>>(wq, wk, wv, wp, wt);
  dim3 gg(128, 4);
  gemm_k<<<gg, 256, 0, stream>>>(h, wt,          bq, nullptr, Qb, nullptr, 0);
  gemm_k<<<gg, 256, 0, stream>>>(h, wt + 262144, bk, nullptr, Kb, nullptr, 0);
  gemm_k<<<gg, 256, 0, stream>>>(h, wt + 524288, bv, nullptr, Vt, nullptr, 1);
  flash_k<<<256, 256, 0, stream>>>(Qb, Kb, Vt, Ob);
  // final projection reads Ob (=h space), x, wt_p; writes d_out (overwrites Q/K)
  gemm_k<<<gg, 256, 0, stream>>>(Ob, wt + 786432, bp, x, nullptr, out, 2);
}